// Round 5
// baseline (227.448 us; speedup 1.0000x reference)
//
#include <hip/hip_runtime.h>
#include <hip/hip_bf16.h>

// LSTM cell, B=4096, IN=1024, H=1024, K = IN+H = 2048. All I/O float32.
// Pass 1 convert_pack: X=concat(input,hx) -> bf16 Xb; W -> bf16 Wp (rows
//   permuted to (gate,hn)-interleaved 128-gate-tile order).
// Pass 2 lstm_gemm2 (R5): 128x128 tile, 1024 blocks (4096/128 x 4096gate/128),
//   4 waves (2x2, 64x64/wave), 32x32x16 MFMA, DOUBLE-buffered LDS (64 KB ->
//   2 blocks/CU resident). Per K-tile: issue next tile's 8 global_load_lds
//   FIRST, compute current tile underneath, then ONE vmcnt(0)+s_barrier.
//   Cross-block TLP (2 independent blocks/CU) hides the per-tile drain --
//   R1-R4 showed intra-block 8-phase scheduling at 1 block/CU stays at
//   ~28% MfmaUtil regardless of staging scheme; R0's 2.6 blocks/CU matched
//   it with no scheduling at all. Bijective XCD swizzle for B-panel L2 reuse.
//   8-slot XOR swizzle (conflict-free ds_read_b128), fused LSTM epilogue
//   with shfl_xor(16) gate exchange (proven R0 layout). fp32 accumulate.

typedef __attribute__((ext_vector_type(8))) __bf16 bf16x8;
typedef __attribute__((ext_vector_type(16))) float f32x16;

__device__ __forceinline__ unsigned short f2bf(float f) {
  union { float f; unsigned int u; } v; v.f = f;
  unsigned int u = v.u + 0x7FFF + ((v.u >> 16) & 1);  // round-to-nearest-even
  return (unsigned short)(u >> 16);
}
__device__ __forceinline__ unsigned int pack2(float a, float b) {
  return (unsigned int)f2bf(a) | ((unsigned int)f2bf(b) << 16);
}

__device__ __forceinline__ void gld_lds16(const void* g, void* l) {
  __builtin_amdgcn_global_load_lds(
      (const __attribute__((address_space(1))) unsigned int*)g,
      (__attribute__((address_space(3))) unsigned int*)l, 16, 0, 0);
}

__device__ __forceinline__ float sigmoidf_fast(float x) {
  return 1.0f / (1.0f + __expf(-x));
}
__device__ __forceinline__ float tanhf_fast(float x) {
  return 1.0f - 2.0f / (__expf(2.0f * x) + 1.0f);
}

// ---------------- Pass 1: fp32 -> bf16 conversion + W permutation ----------
// Wp row q (within 128-row block nb): gate = (q>>4)&3, hn = (q>>6)*16 + (q&15).
__global__ __launch_bounds__(256) void convert_pack(
    const float* __restrict__ xin, const float* __restrict__ hx,
    const float* __restrict__ Wi, const float* __restrict__ Wf,
    const float* __restrict__ Wg, const float* __restrict__ Wo,
    unsigned short* __restrict__ Xb, unsigned short* __restrict__ Wp) {
  const int t = blockIdx.x * 256 + threadIdx.x;
  const float* src;
  unsigned short* dst;
  if (t < (1 << 20)) {
    const int e = t * 8;
    const int row = e >> 11, k = e & 2047;
    src = (k < 1024) ? (xin + (size_t)row * 1024 + k)
                     : (hx + (size_t)row * 1024 + (k - 1024));
    dst = Xb + e;
  } else {
    const int e = (t - (1 << 20)) * 8;
    const int g_rb = e >> 11, k = e & 2047;
    const int nb = g_rb >> 7, rb = g_rb & 127;
    const int gate = (rb >> 4) & 3;
    const int hn = (rb >> 6) * 16 + (rb & 15);
    const float* W = gate == 0 ? Wi : (gate == 1 ? Wf : (gate == 2 ? Wg : Wo));
    src = W + (size_t)(nb * 32 + hn) * 2048 + k;
    dst = Wp + e;
  }
  const float4 lo = *(const float4*)src;
  const float4 hi = *(const float4*)(src + 4);
  uint4 p;
  p.x = pack2(lo.x, lo.y);
  p.y = pack2(lo.z, lo.w);
  p.z = pack2(hi.x, hi.y);
  p.w = pack2(hi.z, hi.w);
  *(uint4*)dst = p;
}

// ---------------- Pass 2: dbuf MFMA GEMM + fused LSTM gating --------------

#define VM0 asm volatile("s_waitcnt vmcnt(0)")
#define BAR __builtin_amdgcn_s_barrier()

// stage one full K-tile (A 16 KB + B 16 KB) into buffer NB at col KC
#define STAGE(NB, KC)                                                          \
  do {                                                                         \
    _Pragma("unroll") for (int d = 0; d < 4; ++d) {                            \
      gld_lds16(asrc + (size_t)d * (32 * 2048) + (KC), lA + (NB)*8192 + d * 2048); \
      gld_lds16(bsrc + (size_t)d * (32 * 2048) + (KC), lB + (NB)*8192 + d * 2048); \
    }                                                                          \
  } while (0)

// compute the current K-tile from buffer CUR (4 k16-steps, 16 MFMAs)
#define COMPUTE(CUR)                                                           \
  do {                                                                         \
    const unsigned short* Ab = As0 + (CUR)*8192;                               \
    const unsigned short* Bb = Bs0 + (CUR)*8192;                               \
    _Pragma("unroll") for (int s = 0; s < 4; ++s) {                            \
      const int cs = ((s * 2 + hi) ^ l7) * 8;                                  \
      bf16x8 a0 = *reinterpret_cast<const bf16x8*>(Ab + aro + cs);             \
      bf16x8 a1 = *reinterpret_cast<const bf16x8*>(Ab + aro + 32 * 64 + cs);   \
      bf16x8 b0 = *reinterpret_cast<const bf16x8*>(Bb + bro + cs);             \
      bf16x8 b1 = *reinterpret_cast<const bf16x8*>(Bb + bro + 32 * 64 + cs);   \
      acc[0][0] = __builtin_amdgcn_mfma_f32_32x32x16_bf16(a0, b0, acc[0][0], 0, 0, 0); \
      acc[0][1] = __builtin_amdgcn_mfma_f32_32x32x16_bf16(a0, b1, acc[0][1], 0, 0, 0); \
      acc[1][0] = __builtin_amdgcn_mfma_f32_32x32x16_bf16(a1, b0, acc[1][0], 0, 0, 0); \
      acc[1][1] = __builtin_amdgcn_mfma_f32_32x32x16_bf16(a1, b1, acc[1][1], 0, 0, 0); \
    }                                                                          \
  } while (0)

// one tile step: prefetch next into CUR^1, compute CUR, single drain+barrier
#define TILE(CUR, KCN)                                                         \
  do {                                                                         \
    STAGE(1 - (CUR), (KCN));                                                   \
    COMPUTE(CUR);                                                              \
    VM0;                                                                       \
    BAR;                                                                       \
  } while (0)

__global__ __launch_bounds__(256, 4) void lstm_gemm2(
    const unsigned short* __restrict__ Xb, const unsigned short* __restrict__ Wp,
    const float* __restrict__ cx,
    const float* __restrict__ bi, const float* __restrict__ bfv,
    const float* __restrict__ bg, const float* __restrict__ bo,
    float* __restrict__ out) {
  __shared__ unsigned short As[2][128 * 64];  // 32 KB: X tile, dbuf
  __shared__ unsigned short Bs[2][128 * 64];  // 32 KB: W tile, dbuf

  const int tid = threadIdx.x;
  const int lane = tid & 63;
  const int wid = tid >> 6;
  const int wr = wid >> 1, wc = wid & 1;
  const int l31 = lane & 31;
  const int hi = lane >> 5;  // k-half within fragment
  const int l7 = l31 & 7;

  // bijective XCD swizzle: 1024 blocks, 8 XCDs, 128 consecutive ids per XCD
  // -> each XCD holds 4 full by-groups (B-panel L2 reuse) x 32 bx values.
  const int bid = blockIdx.y * 32 + blockIdx.x;
  const int swz = (bid & 7) * 128 + (bid >> 3);
  const int bx = swz & 31, by = swz >> 5;

  const int mbase = bx * 128;  // batch tile
  const int nb = by;           // 32-hidden-col (128-gate-col) tile
  const int nbase = nb * 32;

  // staging: slot s holds chunk (s&7)^((s>>3)&7) of row s>>3;
  // thread owns slots tid + 256*d, d=0..3 -> affine sources.
  const int r_base = tid >> 3;
  const int j_sw = (tid & 7) ^ (r_base & 7);
  const unsigned short* asrc = Xb + (size_t)(mbase + r_base) * 2048 + j_sw * 8;
  const unsigned short* bsrc = Wp + (size_t)(nb * 128 + r_base) * 2048 + j_sw * 8;
  unsigned short* lA = &As[0][0] + tid * 8;
  unsigned short* lB = &Bs[0][0] + tid * 8;

  const unsigned short* As0 = &As[0][0];
  const unsigned short* Bs0 = &Bs[0][0];

  f32x16 acc[2][2] = {};  // [ti][tj], 64 AGPRs total

  // fragment row bases: A row = wr*64 + ti*32 + l31; B row = wc*64 + tj*32 + l31
  const int aro = (wr * 64 + l31) * 64;
  const int bro = (wc * 64 + l31) * 64;

  // prologue: tile 0 into buf0
  STAGE(0, 0);
  VM0;
  BAR;

  // tiles 0..29 in pairs (buf0/buf1), then tile 30 (buf0), peel 31 (buf1)
  int kcn = 64;
  for (int it = 0; it < 15; ++it) {
    TILE(0, kcn);
    kcn += 64;
    TILE(1, kcn);
    kcn += 64;
  }
  TILE(0, 31 * 64);   // compute tile 30, prefetch tile 31 into buf1
  COMPUTE(1);          // tile 31, no stage, no drain needed

  // ---- fused LSTM epilogue ----
  // C layout (32x32): col = tj*32 + (lane&31), row = ti*32 + (r&3) + 8*(r>>2)
  //   + 4*(lane>>5). Gate = ((col_local)>>4)&3: lane bit4 (p) selects gate
  //   parity; tj selects {i,f} vs {g,o}. Partner lanes L and L+16 hold the
  //   same (row, hidden-col) for complementary gates -> shfl_xor(16).
  const int p = (l31 >> 4) & 1;  // 0: this lane holds (i,g); 1: (f,o)
  const int n = nbase + wc * 16 + (l31 & 15);
  const float bias0 = p ? bfv[n] : bi[n];
  const float bias1 = p ? bo[n] : bg[n];

  float* outh = out;
  float* outc = out + (size_t)4096 * 1024;

#pragma unroll
  for (int ti = 0; ti < 2; ++ti) {
#pragma unroll
    for (int r = 0; r < 16; ++r) {
      const int row = mbase + wr * 64 + ti * 32 + (r & 3) + 8 * (r >> 2) + 4 * hi;
      const size_t idx = (size_t)row * 1024 + n;
      const float own0 = acc[ti][0][r] + bias0;
      const float own1 = acc[ti][1][r] + bias1;
      const float rcv0 = __shfl_xor(own0, 16);
      const float rcv1 = __shfl_xor(own1, 16);
      const float zi = p ? rcv0 : own0;
      const float zf = p ? own0 : rcv0;
      const float zg = p ? rcv1 : own1;
      const float zo = p ? own1 : rcv1;
      const float it = sigmoidf_fast(zi);
      const float ft = sigmoidf_fast(zf);
      const float gt = tanhf_fast(zg);
      const float ot = sigmoidf_fast(zo);
      const float cv = ft * cx[idx] + it * gt;
      const float hv = ot * tanhf_fast(cv);
      float* dst = p ? (outc + idx) : (outh + idx);
      *dst = p ? cv : hv;
    }
  }
}

// ---------------- Fallback (R2): single fused kernel, no workspace ----------
__global__ __launch_bounds__(256) void lstm_fused_fb(
    const float* __restrict__ xin, const float* __restrict__ hx,
    const float* __restrict__ cx,
    const float* __restrict__ Wi, const float* __restrict__ bi,
    const float* __restrict__ Wf, const float* __restrict__ bfv,
    const float* __restrict__ Wg, const float* __restrict__ bg,
    const float* __restrict__ Wo, const float* __restrict__ bo,
    float* __restrict__ out) {
  typedef __attribute__((ext_vector_type(4))) float f32x4;
  __shared__ unsigned short As[128 * 32];
  __shared__ unsigned short Bs[128 * 32];

  const int tid = threadIdx.x;
  const int lane = tid & 63;
  const int wid = tid >> 6;
  const int wr = wid >> 1, wc = wid & 1;
  const int lane15 = lane & 15, quad = lane >> 4;
  const int mbase = blockIdx.x * 128;
  const int nbase = blockIdx.y * 32;

  const int kofs = (tid & 3) * 8;
  const size_t a_off0 = (size_t)(mbase + (tid >> 2)) * 1024 + kofs;
  const size_t a_off1 = a_off0 + (size_t)64 * 1024;

  auto wsel = [&](int g) { return g == 0 ? Wi : (g == 1 ? Wf : (g == 2 ? Wg : Wo)); };
  const int rb0 = tid >> 2;
  const int rb1 = rb0 + 64;
  const float* bsrc0 =
      wsel((rb0 >> 4) & 3) + (size_t)(nbase + (rb0 >> 6) * 16 + (rb0 & 15)) * 2048 + kofs;
  const float* bsrc1 =
      wsel((rb1 >> 4) & 3) + (size_t)(nbase + (rb1 >> 6) * 16 + (rb1 & 15)) * 2048 + kofs;

  uint4* lA0 = (uint4*)(As + (size_t)tid * 8);
  uint4* lA1 = (uint4*)(As + (size_t)(tid + 256) * 8);
  uint4* lB0 = (uint4*)(Bs + (size_t)tid * 8);
  uint4* lB1 = (uint4*)(Bs + (size_t)(tid + 256) * 8);

  f32x4 acc[4][4] = {};

  for (int kt = 0; kt < 64; ++kt) {
    const int kc = kt * 32;
    const float* abase = (kc < 1024 ? xin : hx) + (kc & 1023);
    const float4 a0lo = *(const float4*)(abase + a_off0);
    const float4 a0hi = *(const float4*)(abase + a_off0 + 4);
    const float4 a1lo = *(const float4*)(abase + a_off1);
    const float4 a1hi = *(const float4*)(abase + a_off1 + 4);
    const float4 b0lo = *(const float4*)(bsrc0 + kc);
    const float4 b0hi = *(const float4*)(bsrc0 + kc + 4);
    const float4 b1lo = *(const float4*)(bsrc1 + kc);
    const float4 b1hi = *(const float4*)(bsrc1 + kc + 4);

    uint4 pa0, pa1, pb0, pb1;
    pa0.x = pack2(a0lo.x, a0lo.y); pa0.y = pack2(a0lo.z, a0lo.w);
    pa0.z = pack2(a0hi.x, a0hi.y); pa0.w = pack2(a0hi.z, a0hi.w);
    pa1.x = pack2(a1lo.x, a1lo.y); pa1.y = pack2(a1lo.z, a1lo.w);
    pa1.z = pack2(a1hi.x, a1hi.y); pa1.w = pack2(a1hi.z, a1hi.w);
    pb0.x = pack2(b0lo.x, b0lo.y); pb0.y = pack2(b0lo.z, b0lo.w);
    pb0.z = pack2(b0hi.x, b0hi.y); pb0.w = pack2(b0hi.z, b0hi.w);
    pb1.x = pack2(b1lo.x, b1lo.y); pb1.y = pack2(b1lo.z, b1lo.w);
    pb1.z = pack2(b1hi.x, b1hi.y); pb1.w = pack2(b1hi.z, b1hi.w);

    __syncthreads();
    *lA0 = pa0; *lA1 = pa1; *lB0 = pb0; *lB1 = pb1;
    __syncthreads();

    bf16x8 aa[4], bb[4];
#pragma unroll
    for (int i = 0; i < 4; ++i)
      aa[i] = *reinterpret_cast<const bf16x8*>(&As[(wr * 64 + i * 16 + lane15) * 32 + quad * 8]);
#pragma unroll
    for (int j = 0; j < 4; ++j)
      bb[j] = *reinterpret_cast<const bf16x8*>(&Bs[(wc * 64 + j * 16 + lane15) * 32 + quad * 8]);
#pragma unroll
    for (int i = 0; i < 4; ++i)
#pragma unroll
      for (int j = 0; j < 4; ++j)
        acc[i][j] = __builtin_amdgcn_mfma_f32_16x16x32_bf16(aa[i], bb[j], acc[i][j], 0, 0, 0);
  }

  const int n = nbase + wc * 16 + lane15;
  const float bias_i = bi[n];
  const float bias_f = bfv[n];
  const float bias_g = bg[n];
  const float bias_o = bo[n];
  float* outh = out;
  float* outc = out + (size_t)4096 * 1024;

#pragma unroll
  for (int i = 0; i < 4; ++i) {
#pragma unroll
    for (int r = 0; r < 4; ++r) {
      const int mb = mbase + wr * 64 + i * 16 + quad * 4 + r;
      const size_t idx = (size_t)mb * 1024 + n;
      const float it = sigmoidf_fast(acc[i][0][r] + bias_i);
      const float ft = sigmoidf_fast(acc[i][1][r] + bias_f);
      const float gt = tanhf_fast(acc[i][2][r] + bias_g);
      const float ot = sigmoidf_fast(acc[i][3][r] + bias_o);
      const float cv = ft * cx[idx] + it * gt;
      const float hv = ot * tanhf_fast(cv);
      outh[idx] = hv;
      outc[idx] = cv;
    }
  }
}

extern "C" void kernel_launch(void* const* d_in, const int* in_sizes, int n_in,
                              void* d_out, int out_size, void* d_ws, size_t ws_size,
                              hipStream_t stream) {
  const float* xin = (const float*)d_in[0];
  const float* hx  = (const float*)d_in[1];
  const float* cx  = (const float*)d_in[2];
  const float* Wi  = (const float*)d_in[3];
  const float* bi  = (const float*)d_in[4];
  const float* Wf  = (const float*)d_in[5];
  const float* bf  = (const float*)d_in[6];
  const float* Wg  = (const float*)d_in[7];
  const float* bg  = (const float*)d_in[8];
  const float* Wo  = (const float*)d_in[9];
  const float* bo  = (const float*)d_in[10];
  float* out = (float*)d_out;

  const size_t need = (size_t)2 * 4096 * 2048 * sizeof(unsigned short);  // 32 MB
  if (ws_size >= need) {
    unsigned short* Xb = (unsigned short*)d_ws;
    unsigned short* Wp = Xb + (size_t)4096 * 2048;
    convert_pack<<<8192, 256, 0, stream>>>(xin, hx, Wi, Wf, Wg, Wo, Xb, Wp);
    dim3 grid(4096 / 128, 1024 / 32);
    lstm_gemm2<<<grid, 256, 0, stream>>>(Xb, Wp, cx, bi, bf, bg, bo, out);
  } else {
    dim3 grid(4096 / 128, 1024 / 32);
    lstm_fused_fb<<<grid, 256, 0, stream>>>(xin, hx, cx, Wi, bi, Wf, bf, Wg, bg, Wo, bo, out);
  }
}

// Round 6
// 205.597 us; speedup vs baseline: 1.1063x; 1.1063x over previous
//
#include <hip/hip_runtime.h>
#include <hip/hip_bf16.h>

// LSTM cell, B=4096, IN=1024, H=1024, K = IN+H = 2048. All I/O float32.
// Pass 1 convert_pack: X=concat(input,hx) -> bf16 Xb; W -> bf16 Wp (rows
//   permuted to the 256-gate-col tile order of pass 2; gates land on the 4
//   N-fragments of one wave -> in-lane gating, no shuffles).
// Pass 2 lstm_gemm16 (R6): faithful m201-geometry port. 256x256 tile, BK=64,
//   512 thr / 8 waves (2M x 4N), 16x16x32 MFMA (m201's frag), [128][64]bf16
//   LDS tiles with st_16x32 swizzle (byte ^= ((byte>>9)&1)<<5) -- the T2
//   conflict fix all prior rounds lacked (they measured exactly 4.0 bank
//   conflicts per ds_read_b128; T2 is the gate for the 8-phase pipeline).
//   Double-buffered 128 KB, 8 phases per 2 K-tiles, one 16KB half-tile
//   staged per phase via global_load_lds x16B with pre-swizzled source,
//   counted s_waitcnt vmcnt(2) at phases 4/8 only. Slot map re-derived with
//   read-window separation: buf0 restaged ph4-7 (reads end ph3), buf1
//   restaged ph8,1,2,3 (reads end ph7). C++ ds_reads (compiler-counted
//   lgkm), raw s_barrier, setprio around MFMA clusters, sched_barrier(0)
//   only after the two vmcnt waits.

typedef __attribute__((ext_vector_type(8))) __bf16 bf16x8;
typedef __attribute__((ext_vector_type(4))) float f32x4;

__device__ __forceinline__ unsigned short f2bf(float f) {
  union { float f; unsigned int u; } v; v.f = f;
  unsigned int u = v.u + 0x7FFF + ((v.u >> 16) & 1);  // round-to-nearest-even
  return (unsigned short)(u >> 16);
}
__device__ __forceinline__ unsigned int pack2(float a, float b) {
  return (unsigned int)f2bf(a) | ((unsigned int)f2bf(b) << 16);
}

__device__ __forceinline__ void gld_lds16(const void* g, void* l) {
  __builtin_amdgcn_global_load_lds(
      (const __attribute__((address_space(1))) unsigned int*)g,
      (__attribute__((address_space(3))) unsigned int*)l, 16, 0, 0);
}

__device__ __forceinline__ float sigmoidf_fast(float x) {
  return 1.0f / (1.0f + __expf(-x));
}
__device__ __forceinline__ float tanhf_fast(float x) {
  return 1.0f - 2.0f / (__expf(2.0f * x) + 1.0f);
}

// ---------------- Pass 1: fp32 -> bf16 conversion + W permutation ----------
// Wp row Q = hb*256 + q, q = wc*64 + gate*16 + h16:
//   gate = (q>>4)&3, hidden = hb*64 + (q>>6)*16 + (q&15).
__global__ __launch_bounds__(256) void convert_pack(
    const float* __restrict__ xin, const float* __restrict__ hx,
    const float* __restrict__ Wi, const float* __restrict__ Wf,
    const float* __restrict__ Wg, const float* __restrict__ Wo,
    unsigned short* __restrict__ Xb, unsigned short* __restrict__ Wp) {
  const int t = blockIdx.x * 256 + threadIdx.x;
  const float* src;
  unsigned short* dst;
  if (t < (1 << 20)) {
    const int e = t * 8;
    const int row = e >> 11, k = e & 2047;
    src = (k < 1024) ? (xin + (size_t)row * 1024 + k)
                     : (hx + (size_t)row * 1024 + (k - 1024));
    dst = Xb + e;
  } else {
    const int e = (t - (1 << 20)) * 8;
    const int q = e >> 11, k = e & 2047;
    const int hb = q >> 8, rem = q & 255;
    const int wcp = rem >> 6, gate = (rem >> 4) & 3, h16 = rem & 15;
    const int hidden = hb * 64 + wcp * 16 + h16;
    const float* W = gate == 0 ? Wi : (gate == 1 ? Wf : (gate == 2 ? Wg : Wo));
    src = W + (size_t)hidden * 2048 + k;
    dst = Wp + e;
  }
  const float4 lo = *(const float4*)src;
  const float4 hi = *(const float4*)(src + 4);
  uint4 p;
  p.x = pack2(lo.x, lo.y);
  p.y = pack2(lo.z, lo.w);
  p.z = pack2(hi.x, hi.y);
  p.w = pack2(hi.z, hi.w);
  *(uint4*)dst = p;
}

// ---------------- Pass 2: 8-phase 16x16x32 GEMM + fused LSTM gating --------

#define BAR __builtin_amdgcn_s_barrier()
#define SP1 __builtin_amdgcn_s_setprio(1)
#define SP0 __builtin_amdgcn_s_setprio(0)
#define VMW2                                    \
  do {                                          \
    asm volatile("s_waitcnt vmcnt(2)");         \
    __builtin_amdgcn_sched_barrier(0);          \
  } while (0)
#define VMW0                                    \
  do {                                          \
    asm volatile("s_waitcnt vmcnt(0)");         \
    __builtin_amdgcn_sched_barrier(0);          \
  } while (0)

// stage one 16KB half-tile (2 x 8KB units) of tile KT into buffer BUF
#define STG_A(BUF, H, KT)                                                     \
  do {                                                                        \
    gld_lds16(aSrc + (size_t)((H)*128) * 2048 + (KT)*64,                      \
              aDst + (BUF)*16384 + (H)*8192);                                 \
    gld_lds16(aSrc + (size_t)((H)*128 + 64) * 2048 + (KT)*64,                 \
              aDst + (BUF)*16384 + (H)*8192 + 4096);                          \
  } while (0)
#define STG_B(BUF, H, KT)                                                     \
  do {                                                                        \
    gld_lds16(bSrc + (size_t)((H)*128) * 2048 + (KT)*64,                      \
              bDst + (BUF)*16384 + (H)*8192);                                 \
    gld_lds16(bSrc + (size_t)((H)*128 + 64) * 2048 + (KT)*64,                 \
              bDst + (BUF)*16384 + (H)*8192 + 4096);                          \
  } while (0)

// ds_reads: swizzled via per-lane q4x (st_16x32: pos bit1 ^= row bit2)
#define RD_A(BUF, MB)                                                         \
  _Pragma("unroll") for (int m = 0; m < 4; ++m)                               \
  _Pragma("unroll") for (int s = 0; s < 2; ++s)                               \
      a[m][s] = *(const bf16x8*)(Asb + (BUF)*16384 + aro + ((MB) + m) * 1024 +\
                                 s * 32);
#define RD_B(BUF, GB)                                                         \
  _Pragma("unroll") for (int g = 0; g < 2; ++g)                               \
  _Pragma("unroll") for (int s = 0; s < 2; ++s)                               \
      b[(GB) + g][s] = *(const bf16x8*)(Bsb + (BUF)*16384 + bro +             \
                                        ((GB) + g) * 1024 + s * 32);
// 16 MFMAs: C-quadrant (m MB..MB+3) x (g GB..GB+1) x full K=64
#define MM16(MB, GB)                                                          \
  _Pragma("unroll") for (int s = 0; s < 2; ++s)                               \
  _Pragma("unroll") for (int m = 0; m < 4; ++m)                               \
  _Pragma("unroll") for (int g = 0; g < 2; ++g)                               \
      acc[(MB) + m][(GB) + g] = __builtin_amdgcn_mfma_f32_16x16x32_bf16(      \
          a[m][s], b[(GB) + g][s], acc[(MB) + m][(GB) + g], 0, 0, 0);

__global__ __launch_bounds__(512, 2) void lstm_gemm16(
    const unsigned short* __restrict__ Xb, const unsigned short* __restrict__ Wp,
    const float* __restrict__ cx,
    const float* __restrict__ bi, const float* __restrict__ bfv,
    const float* __restrict__ bg, const float* __restrict__ bo,
    float* __restrict__ out) {
  // A: [buf][Mhalf 2][128 rows][64 k] bf16, st_16x32-swizzled. 64 KB.
  // B: [buf][Nhalf 2][128 rows][64 k] bf16, same. 64 KB.
  __shared__ unsigned short As[32768];
  __shared__ unsigned short Bs[32768];

  const int tid = threadIdx.x;
  const int lane = tid & 63;
  const int wid = tid >> 6;         // 0..7
  const int wr = wid >> 2;          // 0..1: M-half (128 rows)
  const int wc = wid & 3;           // 0..3: N 64-col slice (16 hidden x 4 gates)
  const int l15 = lane & 15;
  const int q4 = (lane >> 4) & 3;   // k-chunk quarter
  // st_16x32 read swizzle: flip pos bit1 by row bit2 (= l15 bit2, m/g-invariant)
  const int q4x = q4 ^ ((l15 >> 2) & 1) * 2;

  const int mbase = blockIdx.x * 256;  // batch tile
  const int hb = blockIdx.y;           // 64-hidden block (256 gate-cols)

  // ---- staging: thread t -> unit row r8=t>>3, pre-swizzled chunk jx --------
  const int r8 = tid >> 3;                            // 0..63
  const int jx = (tid & 7) ^ (((tid >> 5) & 1) * 2);  // inverse st_16x32
  const unsigned short* aSrc = Xb + (size_t)(mbase + r8) * 2048 + jx * 8;
  const unsigned short* bSrc = Wp + (size_t)(hb * 256 + r8) * 2048 + jx * 8;
  unsigned short* aDst = As + tid * 8;
  unsigned short* bDst = Bs + tid * 8;

  const unsigned short* Asb = As;
  const unsigned short* Bsb = Bs;
  // per-lane read bases (shorts)
  const int aro = wr * 8192 + l15 * 64 + q4x * 8;
  const int bro = (wc >> 1) * 8192 + (wc & 1) * 4096 + l15 * 64 + q4x * 8;

  f32x4 acc[8][4] = {};  // [m-frag][gate], 128 regs
  bf16x8 a[4][2], b[4][2];

  // ---- prologue: buf0 <- tile0 (4 halves), buf1.A-h0 <- tile1 -------------
  STG_A(0, 0, 0); STG_A(0, 1, 0); STG_B(0, 0, 0); STG_B(0, 1, 0);
  STG_A(1, 0, 1);
  VMW2;  // oldest 8 (all of buf0) landed
  BAR;

  // ---- main loop: 15 iters x 2 K-tiles; iter peeled for tiles 30/31 -------
  for (int i = 0; i < 15; ++i) {
    const int kt = 2 * i;
    // ph1: compute buf0 q(m0-3, g0-1); finish staging buf1 <- kt+1
    RD_A(0, 0); RD_B(0, 0);
    STG_A(1, 1, kt + 1);
    BAR; SP1; MM16(0, 0); SP0; BAR;
    // ph2: q(m0-3, g2-3)
    RD_B(0, 2);
    STG_B(1, 0, kt + 1);
    BAR; SP1; MM16(0, 2); SP0; BAR;
    // ph3: q(m4-7, g2-3)  (buf0 reads end here)
    RD_A(0, 4);
    STG_B(1, 1, kt + 1);
    BAR; SP1; MM16(4, 2); SP0; BAR;
    // ph4: q(m4-7, g0-1) from regs; start restaging buf0 <- kt+2;
    //      counted wait: buf1 (kt+1) fully landed before ph5 reads
    STG_A(0, 0, kt + 2);
    BAR; SP1; MM16(4, 0); SP0; VMW2; BAR;
    // ph5: compute buf1 q(m0-3, g0-1)
    RD_A(1, 0); RD_B(1, 0);
    STG_A(0, 1, kt + 2);
    BAR; SP1; MM16(0, 0); SP0; BAR;
    // ph6
    RD_B(1, 2);
    STG_B(0, 0, kt + 2);
    BAR; SP1; MM16(0, 2); SP0; BAR;
    // ph7  (buf1 reads end here)
    RD_A(1, 4);
    STG_B(0, 1, kt + 2);
    BAR; SP1; MM16(4, 2); SP0; BAR;
    // ph8: start staging buf1 <- kt+3; counted wait: buf0 (kt+2) landed
    STG_A(1, 0, kt + 3);
    BAR; SP1; MM16(4, 0); SP0; VMW2; BAR;
  }
  // ---- peel: tiles 30 (buf0) / 31 (buf1); ph1-3 finish staging tile 31 ----
  RD_A(0, 0); RD_B(0, 0);
  STG_A(1, 1, 31);
  BAR; SP1; MM16(0, 0); SP0; BAR;
  RD_B(0, 2);
  STG_B(1, 0, 31);
  BAR; SP1; MM16(0, 2); SP0; BAR;
  RD_A(0, 4);
  STG_B(1, 1, 31);
  BAR; SP1; MM16(4, 2); SP0; BAR;
  BAR; SP1; MM16(4, 0); SP0; VMW0; BAR;  // drain: tile 31 fully in LDS
  RD_A(1, 0); RD_B(1, 0);
  BAR; SP1; MM16(0, 0); SP0; BAR;
  RD_B(1, 2);
  BAR; SP1; MM16(0, 2); SP0; BAR;
  RD_A(1, 4);
  BAR; SP1; MM16(4, 2); SP0; BAR;
  SP1; MM16(4, 0); SP0;

  // ---- fused LSTM epilogue: all 4 gates in-lane (gate = N-frag g) ---------
  // C 16x16 layout: col = l15 (hidden), row = q4*4 + ii.
  const int h = hb * 64 + wc * 16 + l15;
  const float bias_i = bi[h];
  const float bias_f = bfv[h];
  const float bias_g = bg[h];
  const float bias_o = bo[h];

  float* outh = out;
  float* outc = out + (size_t)4096 * 1024;

#pragma unroll
  for (int m = 0; m < 8; ++m) {
#pragma unroll
    for (int ii = 0; ii < 4; ++ii) {
      const int row = mbase + wr * 128 + m * 16 + q4 * 4 + ii;
      const size_t idx = (size_t)row * 1024 + h;
      const float it = sigmoidf_fast(acc[m][0][ii] + bias_i);
      const float ft = sigmoidf_fast(acc[m][1][ii] + bias_f);
      const float gt = tanhf_fast(acc[m][2][ii] + bias_g);
      const float ot = sigmoidf_fast(acc[m][3][ii] + bias_o);
      const float cv = ft * cx[idx] + it * gt;
      const float hv = ot * tanhf_fast(cv);
      outh[idx] = hv;
      outc[idx] = cv;
    }
  }
}

// ---------------- Fallback (R2): single fused kernel, no workspace ----------
__global__ __launch_bounds__(256) void lstm_fused_fb(
    const float* __restrict__ xin, const float* __restrict__ hx,
    const float* __restrict__ cx,
    const float* __restrict__ Wi, const float* __restrict__ bi,
    const float* __restrict__ Wf, const float* __restrict__ bfv,
    const float* __restrict__ Wg, const float* __restrict__ bg,
    const float* __restrict__ Wo, const float* __restrict__ bo,
    float* __restrict__ out) {
  __shared__ unsigned short As[128 * 32];
  __shared__ unsigned short Bs[128 * 32];

  const int tid = threadIdx.x;
  const int lane = tid & 63;
  const int wid = tid >> 6;
  const int wr = wid >> 1, wc = wid & 1;
  const int lane15 = lane & 15, quad = lane >> 4;
  const int mbase = blockIdx.x * 128;
  const int nbase = blockIdx.y * 32;

  const int kofs = (tid & 3) * 8;
  const size_t a_off0 = (size_t)(mbase + (tid >> 2)) * 1024 + kofs;
  const size_t a_off1 = a_off0 + (size_t)64 * 1024;

  auto wsel = [&](int g) { return g == 0 ? Wi : (g == 1 ? Wf : (g == 2 ? Wg : Wo)); };
  const int rb0 = tid >> 2;
  const int rb1 = rb0 + 64;
  const float* bsrc0 =
      wsel((rb0 >> 4) & 3) + (size_t)(nbase + (rb0 >> 6) * 16 + (rb0 & 15)) * 2048 + kofs;
  const float* bsrc1 =
      wsel((rb1 >> 4) & 3) + (size_t)(nbase + (rb1 >> 6) * 16 + (rb1 & 15)) * 2048 + kofs;

  uint4* lA0 = (uint4*)(As + (size_t)tid * 8);
  uint4* lA1 = (uint4*)(As + (size_t)(tid + 256) * 8);
  uint4* lB0 = (uint4*)(Bs + (size_t)tid * 8);
  uint4* lB1 = (uint4*)(Bs + (size_t)(tid + 256) * 8);

  f32x4 acc[4][4] = {};

  for (int kt = 0; kt < 64; ++kt) {
    const int kc = kt * 32;
    const float* abase = (kc < 1024 ? xin : hx) + (kc & 1023);
    const float4 a0lo = *(const float4*)(abase + a_off0);
    const float4 a0hi = *(const float4*)(abase + a_off0 + 4);
    const float4 a1lo = *(const float4*)(abase + a_off1);
    const float4 a1hi = *(const float4*)(abase + a_off1 + 4);
    const float4 b0lo = *(const float4*)(bsrc0 + kc);
    const float4 b0hi = *(const float4*)(bsrc0 + kc + 4);
    const float4 b1lo = *(const float4*)(bsrc1 + kc);
    const float4 b1hi = *(const float4*)(bsrc1 + kc + 4);

    uint4 pa0, pa1, pb0, pb1;
    pa0.x = pack2(a0lo.x, a0lo.y); pa0.y = pack2(a0lo.z, a0lo.w);
    pa0.z = pack2(a0hi.x, a0hi.y); pa0.w = pack2(a0hi.z, a0hi.w);
    pa1.x = pack2(a1lo.x, a1lo.y); pa1.y = pack2(a1lo.z, a1lo.w);
    pa1.z = pack2(a1hi.x, a1hi.y); pa1.w = pack2(a1hi.z, a1hi.w);
    pb0.x = pack2(b0lo.x, b0lo.y); pb0.y = pack2(b0lo.z, b0lo.w);
    pb0.z = pack2(b0hi.x, b0hi.y); pb0.w = pack2(b0hi.z, b0hi.w);
    pb1.x = pack2(b1lo.x, b1lo.y); pb1.y = pack2(b1lo.z, b1lo.w);
    pb1.z = pack2(b1hi.x, b1hi.y); pb1.w = pack2(b1hi.z, b1hi.w);

    __syncthreads();
    *lA0 = pa0; *lA1 = pa1; *lB0 = pb0; *lB1 = pb1;
    __syncthreads();

    bf16x8 aa[4], bb[4];
#pragma unroll
    for (int i = 0; i < 4; ++i)
      aa[i] = *reinterpret_cast<const bf16x8*>(&As[(wr * 64 + i * 16 + lane15) * 32 + quad * 8]);
#pragma unroll
    for (int j = 0; j < 4; ++j)
      bb[j] = *reinterpret_cast<const bf16x8*>(&Bs[(wc * 64 + j * 16 + lane15) * 32 + quad * 8]);
#pragma unroll
    for (int i = 0; i < 4; ++i)
#pragma unroll
      for (int j = 0; j < 4; ++j)
        acc[i][j] = __builtin_amdgcn_mfma_f32_16x16x32_bf16(aa[i], bb[j], acc[i][j], 0, 0, 0);
  }

  const int n = nbase + wc * 16 + lane15;
  const float bias_i = bi[n];
  const float bias_f = bfv[n];
  const float bias_g = bg[n];
  const float bias_o = bo[n];
  float* outh = out;
  float* outc = out + (size_t)4096 * 1024;

#pragma unroll
  for (int i = 0; i < 4; ++i) {
#pragma unroll
    for (int r = 0; r < 4; ++r) {
      const int mb = mbase + wr * 64 + i * 16 + quad * 4 + r;
      const size_t idx = (size_t)mb * 1024 + n;
      const float it = sigmoidf_fast(acc[i][0][r] + bias_i);
      const float ft = sigmoidf_fast(acc[i][1][r] + bias_f);
      const float gt = tanhf_fast(acc[i][2][r] + bias_g);
      const float ot = sigmoidf_fast(acc[i][3][r] + bias_o);
      const float cv = ft * cx[idx] + it * gt;
      const float hv = ot * tanhf_fast(cv);
      outh[idx] = hv;
      outc[idx] = cv;
    }
  }
}

extern "C" void kernel_launch(void* const* d_in, const int* in_sizes, int n_in,
                              void* d_out, int out_size, void* d_ws, size_t ws_size,
                              hipStream_t stream) {
  const float* xin = (const float*)d_in[0];
  const float* hx  = (const float*)d_in[1];
  const float* cx  = (const float*)d_in[2];
  const float* Wi  = (const float*)d_in[3];
  const float* bi  = (const float*)d_in[4];
  const float* Wf  = (const float*)d_in[5];
  const float* bf  = (const float*)d_in[6];
  const float* Wg  = (const float*)d_in[7];
  const float* bg  = (const float*)d_in[8];
  const float* Wo  = (const float*)d_in[9];
  const float* bo  = (const float*)d_in[10];
  float* out = (float*)d_out;

  const size_t need = (size_t)2 * 4096 * 2048 * sizeof(unsigned short);  // 32 MB
  if (ws_size >= need) {
    unsigned short* Xb = (unsigned short*)d_ws;
    unsigned short* Wp = Xb + (size_t)4096 * 2048;
    convert_pack<<<8192, 256, 0, stream>>>(xin, hx, Wi, Wf, Wg, Wo, Xb, Wp);
    dim3 grid(4096 / 256, 4096 / 256);
    lstm_gemm16<<<grid, 512, 0, stream>>>(Xb, Wp, cx, bi, bf, bg, bo, out);
  } else {
    dim3 grid(4096 / 128, 1024 / 32);
    lstm_fused_fb<<<grid, 256, 0, stream>>>(xin, hx, cx, Wi, bi, Wf, bf, Wg, bg, Wo, bo, out);
  }
}